// Round 1
// baseline (33.892 us; speedup 1.0000x reference)
//
#include <hip/hip_runtime.h>

#define TLEN 4096
#define NTHREADS 256
#define PER (TLEN / NTHREADS)   // 16

__global__ __launch_bounds__(NTHREADS) void swt_db4_l3_kernel(
    const float* __restrict__ x,
    const float* __restrict__ lo_g,
    const float* __restrict__ hi_g,
    float* __restrict__ out)
{
    __shared__ float bufA[TLEN];
    __shared__ float bufB[TLEN];

    const int row = blockIdx.x;          // 0 .. B*N-1
    const int tid = threadIdx.x;

    // broadcast filter loads (same addr all lanes -> L1 hit)
    float lo[8], hi[8];
#pragma unroll
    for (int j = 0; j < 8; ++j) { lo[j] = lo_g[j]; hi[j] = hi_g[j]; }

    const float* xr = x + (size_t)row * TLEN;

    // Stage the whole row into LDS, vectorized float4, coalesced.
#pragma unroll
    for (int k = 0; k < PER / 4; ++k) {
        int idx = (tid + k * NTHREADS) * 4;
        float4 v = *reinterpret_cast<const float4*>(xr + idx);
        bufA[idx + 0] = v.x; bufA[idx + 1] = v.y;
        bufA[idx + 2] = v.z; bufA[idx + 3] = v.w;
    }
    __syncthreads();

    float D1[PER], D2[PER], D3[PER], A3[PER];

    // ---- Level 1: dil = 1, bufA -> (D1 regs, A1 -> bufB) ----
#pragma unroll
    for (int k = 0; k < PER; ++k) {
        int t = tid + k * NTHREADS;
        float a = 0.f, d = 0.f;
#pragma unroll
        for (int j = 0; j < 8; ++j) {
            float v = bufA[(t + (4 - j)) & (TLEN - 1)];
            a = fmaf(lo[j], v, a);
            d = fmaf(hi[j], v, d);
        }
        D1[k] = d;
        bufB[t] = a;
    }
    __syncthreads();

    // ---- Level 2: dil = 2, bufB -> (D2 regs, A2 -> bufA) ----
#pragma unroll
    for (int k = 0; k < PER; ++k) {
        int t = tid + k * NTHREADS;
        float a = 0.f, d = 0.f;
#pragma unroll
        for (int j = 0; j < 8; ++j) {
            float v = bufB[(t + (4 - j) * 2) & (TLEN - 1)];
            a = fmaf(lo[j], v, a);
            d = fmaf(hi[j], v, d);
        }
        D2[k] = d;
        bufA[t] = a;
    }
    __syncthreads();

    // ---- Level 3: dil = 4, bufA -> (D3, A3 regs) ----
#pragma unroll
    for (int k = 0; k < PER; ++k) {
        int t = tid + k * NTHREADS;
        float a = 0.f, d = 0.f;
#pragma unroll
        for (int j = 0; j < 8; ++j) {
            float v = bufA[(t + (4 - j) * 4) & (TLEN - 1)];
            a = fmaf(lo[j], v, a);
            d = fmaf(hi[j], v, d);
        }
        D3[k] = d;
        A3[k] = a;
    }

    // ---- Store: out[row][t][0..3] = {A3, D3, D2, D1}; one float4 per t ----
    float4* outr = reinterpret_cast<float4*>(out + (size_t)row * TLEN * 4);
#pragma unroll
    for (int k = 0; k < PER; ++k) {
        int t = tid + k * NTHREADS;
        outr[t] = make_float4(A3[k], D3[k], D2[k], D1[k]);
    }
}

extern "C" void kernel_launch(void* const* d_in, const int* in_sizes, int n_in,
                              void* d_out, int out_size, void* d_ws, size_t ws_size,
                              hipStream_t stream) {
    const float* x  = (const float*)d_in[0];
    const float* lo = (const float*)d_in[1];
    const float* hi = (const float*)d_in[2];
    float* out = (float*)d_out;

    const int rows = 64 * 32;   // B * N
    swt_db4_l3_kernel<<<dim3(rows), dim3(NTHREADS), 0, stream>>>(x, lo, hi, out);
}